// Round 8
// baseline (356.150 us; speedup 1.0000x reference)
//
#include <hip/hip_runtime.h>

#define B_ 32
#define N_ 4096
#define ENC_ 1024
#define DEC_ 512
#define ATT_ 512

typedef __attribute__((ext_vector_type(8))) short short8;
typedef __attribute__((ext_vector_type(4))) float f32x4;

// fp32 -> bf16 bits, round-to-nearest-even (finite inputs)
__device__ __forceinline__ short f2bf(float f) {
  union { float f; unsigned u; } x; x.f = f;
  unsigned r = (x.u + 0x7FFFu + ((x.u >> 16) & 1u)) >> 16;
  return (short)r;
}

// async global->LDS DMA, 16B/lane; LDS dest = wave-uniform base + lane*16,
// global source is PER-LANE (pre-swizzled source implements the LDS swizzle).
__device__ __forceinline__ void gl_lds16(const float* g, void* l) {
  __builtin_amdgcn_global_load_lds(
      (const __attribute__((address_space(1))) unsigned int*)g,
      (__attribute__((address_space(3))) unsigned int*)l, 16, 0, 0);
}

// ---------------------------------------------------------------------------
// Kernel 1: (a) att2[b,a] = dh[b,:]@W_dec[:,a] + b_dec[a] + b_enc[a]
//           (b) W_enc fp32 -> bf16 in MFMA B-fragment order:
//               Wfrag[((c*32+g)*64+l)*8+j] = W_enc[g*32+(l>>4)*8+j][c*16+(l&15)]
// ---------------------------------------------------------------------------
extern "C" __global__ void __launch_bounds__(256) prep_kernel(
    const float* __restrict__ dh, const float* __restrict__ W_dec,
    const float* __restrict__ b_dec, const float* __restrict__ b_enc,
    const float* __restrict__ W_enc,
    float* __restrict__ att2, short* __restrict__ Wfrag)
{
  if (blockIdx.x < B_) {
    __shared__ float dhs[DEC_];
    int b = blockIdx.x;
    for (int i = threadIdx.x; i < DEC_; i += 256) dhs[i] = dh[b * DEC_ + i];
    __syncthreads();
    for (int a = threadIdx.x; a < ATT_; a += 256) {
      float s = b_dec[a] + b_enc[a];
      for (int k = 0; k < DEC_; ++k) s += dhs[k] * W_dec[k * ATT_ + a];
      att2[b * ATT_ + a] = s;
    }
  } else {
    int idx = (blockIdx.x - B_) * 256 + threadIdx.x;  // 0..65535 chunks of 8
    int l = idx & 63;          // lane
    int g = (idx >> 6) & 31;   // k-chunk (32 chunks of K=32)
    int c = idx >> 11;         // col-fragment (32 of 16 cols)
    int col = c * 16 + (l & 15);
    int kb = g * 32 + (l >> 4) * 8;
    short8 p;
#pragma unroll
    for (int j = 0; j < 8; ++j) p[j] = f2bf(W_enc[(kb + j) * ATT_ + col]);
    *(short8*)(Wfrag + ((long)idx << 3)) = p;
  }
}

// ---------------------------------------------------------------------------
// Kernel 2: fused  e_part[h,b,n] = sum_{a in half h} relu(att1+att2)*w
// m97-style structure adapted to fp32 A:
//  - 256-thread blocks (4 waves x 64x64), tile 64 rows x 256 cols; col-half
//    siblings 8 apart in blockIdx (same XCD) so A re-read hits L2.
//  - A staged as FP32 via global_load_lds into XOR-swizzled [64][64] LDS
//    (linear DMA dest + inverse-swizzled per-lane SOURCE; swizzled ds_read).
//    Converted fp32->bf16 at fragment read. Staging never touches VGPRs.
//  - B register-streamed from L2-resident fragment-ordered Wfrag.
//  - BK=64, one __syncthreads per step (DMA issued ~700cyc before drain).
//  - ~127 VGPR target, launch_bounds(256,3) -> 3 blocks/CU (3 barrier
//    domains co-resident = m114 latency hiding).
// ---------------------------------------------------------------------------
extern "C" __global__ void __launch_bounds__(256, 3) gemm_e_kernel(
    const float* __restrict__ enc, const short* __restrict__ Wfrag,
    const float* __restrict__ att2, const float* __restrict__ w_full,
    float* __restrict__ e_part)
{
  __shared__ __align__(16) float As[2][64 * 64];   // fp32, 16 KB each
  __shared__ float e_red[64][4];

  const int tid = threadIdx.x;
  const int lane = tid & 63;
  const int w = tid >> 6;          // wave 0..3 -> cols h*256 + w*64 ..
  const int blk = blockIdx.x;      // 4096 = 256 groups x {h=0:8, h=1:8}
  const int g16 = blk >> 4;
  const int h = (blk >> 3) & 1;    // column half
  const int p = g16 * 8 + (blk & 7);
  const int b = p >> 6;
  const int n0 = (p & 63) * 64;

  const int qv = lane >> 4;        // 0..3
  const int ch = lane & 15;        // 16B chunk within 64-float row slice

  // ---- A staging sources (inverse-swizzled). Wave w stages rows w*16..+15.
  // DMA j (0..3): dest row_local = j*4 + qv, dest chunk = ch;
  // content = src chunk ch ^ (row_local & 7);  (j*4)&7 = (j&1)*4.
  const float* asrc[4];
#pragma unroll
  for (int j = 0; j < 4; ++j) {
    int rl = j * 4 + qv;
    asrc[j] = enc + (long)(b * N_ + n0 + w * 16 + rl) * ENC_ +
              ((ch ^ ((qv + (j & 1) * 4) & 7)) << 2);
  }
  // LDS dest byte base for this wave (HW adds lane*16)
  // dest for DMA j = dbase + j*1024 within the active buffer.

  // ---- A fragment read bases (swizzle mask m = lane&7 is r-independent):
  // addr(r,ks,half) = abase[half] + r*4096 + ks*128   (imm-foldable)
  const int abase0 = ch * 256 + (((qv * 2 + 0) ^ (ch & 7)) << 4);
  const int abase1 = ch * 256 + (((qv * 2 + 1) ^ (ch & 7)) << 4);

  // ---- B fragments: col-frag cf = h*16 + w*4 + cc, k-chunk g32 at
  // Wfrag[(cf*32+g32)*512 + lane*8]
  const short* bptr = Wfrag + (long)(h * 16 + w * 4) * 16384 + lane * 8;

  f32x4 acc[4][4] = {};

  // ---- prologue: DMA-stage A(step 0) into As[0]
  {
    char* d = (char*)(&As[0][0]) + (w << 12);
#pragma unroll
    for (int j = 0; j < 4; ++j) gl_lds16(asrc[j], d + j * 1024);
  }
  __syncthreads();

  // ---- main K loop: 16 steps of BK=64
#pragma unroll
  for (int t = 0; t < 16; ++t) {
    const int cur = t & 1;
    // async prefetch A(t+1) into the other buffer (drained at end barrier)
    if (t + 1 < 16) {
      char* d = (char*)(&As[cur ^ 1][0]) + (w << 12);
#pragma unroll
      for (int j = 0; j < 4; ++j)
        gl_lds16(asrc[j] + (t + 1) * 64, d + j * 1024);
    }
#pragma unroll
    for (int ks = 0; ks < 2; ++ks) {
      short8 bfg[4];
#pragma unroll
      for (int cc = 0; cc < 4; ++cc)
        bfg[cc] = *(const short8*)(bptr + cc * 16384 + (2 * t + ks) * 512);
      short8 af[4];
#pragma unroll
      for (int r = 0; r < 4; ++r) {
        f32x4 lo = *(const f32x4*)((const char*)(&As[cur][0]) +
                                   (abase0 + r * 4096 + ks * 128));
        f32x4 hi = *(const f32x4*)((const char*)(&As[cur][0]) +
                                   (abase1 + r * 4096 + ks * 128));
#pragma unroll
        for (int j = 0; j < 4; ++j) {
          af[r][j] = f2bf(lo[j]);
          af[r][j + 4] = f2bf(hi[j]);
        }
      }
      __builtin_amdgcn_s_setprio(1);
#pragma unroll
      for (int cc = 0; cc < 4; ++cc)
#pragma unroll
        for (int r = 0; r < 4; ++r)
          acc[r][cc] = __builtin_amdgcn_mfma_f32_16x16x32_bf16(
              af[r], bfg[cc], acc[r][cc], 0, 0, 0);
      __builtin_amdgcn_s_setprio(0);
    }
    __syncthreads();   // drains A(t+1) DMA + all LDS reads of As[cur]
  }

  // ---- epilogue: partial e over this block's 256 cols
  const int lq = lane >> 4, lr = lane & 15;
  float at2v[4], wv[4];
#pragma unroll
  for (int c = 0; c < 4; ++c) {
    int col = h * 256 + w * 64 + c * 16 + lr;
    at2v[c] = att2[b * ATT_ + col];
    wv[c] = w_full[col];
  }
#pragma unroll
  for (int r = 0; r < 4; ++r) {
#pragma unroll
    for (int j = 0; j < 4; ++j) {
      float s = 0.f;
#pragma unroll
      for (int c = 0; c < 4; ++c)
        s += fmaxf(acc[r][c][j] + at2v[c], 0.f) * wv[c];
      s += __shfl_xor(s, 1); s += __shfl_xor(s, 2);
      s += __shfl_xor(s, 4); s += __shfl_xor(s, 8);
      if (lr == 0) e_red[r * 16 + lq * 4 + j][w] = s;
    }
  }
  __syncthreads();
  if (tid < 64) {
    float ev = e_red[tid][0] + e_red[tid][1] + e_red[tid][2] + e_red[tid][3];
    e_part[(long)h * (B_ * N_) + b * N_ + n0 + tid] = ev;
  }
}

// ---------------------------------------------------------------------------
// Kernel 3: softmax over N per batch, summing the two column-half partials.
// ---------------------------------------------------------------------------
extern "C" __global__ void __launch_bounds__(256) softmax_kernel(
    const float* __restrict__ e, float* __restrict__ alpha)
{
  int b = blockIdx.x, tid = threadIdx.x;
  float v[16];
  float m = -1e30f;
#pragma unroll
  for (int i = 0; i < 16; ++i) {
    int idx = b * N_ + i * 256 + tid;
    v[i] = e[idx] + e[B_ * N_ + idx];
    m = fmaxf(m, v[i]);
  }
  for (int off = 1; off < 64; off <<= 1) m = fmaxf(m, __shfl_xor(m, off));
  __shared__ float redm[4];
  if ((tid & 63) == 0) redm[tid >> 6] = m;
  __syncthreads();
  m = fmaxf(fmaxf(redm[0], redm[1]), fmaxf(redm[2], redm[3]));
  float s = 0.f;
#pragma unroll
  for (int i = 0; i < 16; ++i) { v[i] = expf(v[i] - m); s += v[i]; }
  for (int off = 1; off < 64; off <<= 1) s += __shfl_xor(s, off);
  __shared__ float reds[4];
  if ((tid & 63) == 0) reds[tid >> 6] = s;
  __syncthreads();
  s = reds[0] + reds[1] + reds[2] + reds[3];
  float inv = 1.0f / s;
#pragma unroll
  for (int i = 0; i < 16; ++i) alpha[b * N_ + i * 256 + tid] = v[i] * inv;
}

// ---------------------------------------------------------------------------
// Kernel 4: partial awe. grid = b(32) x cchunk(4, 256 cols) x nchunk(16, 256 n)
// ---------------------------------------------------------------------------
extern "C" __global__ void __launch_bounds__(256) awe_part_kernel(
    const float* __restrict__ enc, const float* __restrict__ alpha,
    float* __restrict__ part)
{
  __shared__ float als[256];
  __shared__ f32x4 red[256];
  int bi = blockIdx.x;
  int b = bi & 31, cchunk = (bi >> 5) & 3, nchunk = bi >> 7;
  int t = threadIdx.x;
  int n0 = nchunk * 256;
  als[t] = alpha[b * N_ + n0 + t];
  __syncthreads();
  int tcol = t & 63, tn = t >> 6;
  const float* base = enc + (long)b * N_ * ENC_ + (long)n0 * ENC_ +
                      cchunk * 256 + tcol * 4;
  f32x4 acc = {};
  for (int i = tn; i < 256; i += 4) {
    f32x4 vv = *(const f32x4*)(base + (long)i * ENC_);
    acc += als[i] * vv;
  }
  red[t] = acc;
  __syncthreads();
  if (t < 64) {
    f32x4 s = red[t] + red[t + 64] + red[t + 128] + red[t + 192];
    *(f32x4*)(&part[(long)nchunk * 32768 + b * 1024 + cchunk * 256 + t * 4]) = s;
  }
}

// Kernel 5: combine the 16 n-partials
extern "C" __global__ void __launch_bounds__(256) awe_reduce_kernel(
    const float* __restrict__ part, float* __restrict__ awe)
{
  int i = blockIdx.x * 256 + threadIdx.x;   // 32768 = 32*1024
  float s = 0.f;
#pragma unroll
  for (int p = 0; p < 16; ++p) s += part[(long)p * 32768 + i];
  awe[i] = s;
}

// ---------------------------------------------------------------------------
extern "C" void kernel_launch(void* const* d_in, const int* in_sizes, int n_in,
                              void* d_out, int out_size, void* d_ws, size_t ws_size,
                              hipStream_t stream) {
  const float* enc    = (const float*)d_in[0];
  const float* dh     = (const float*)d_in[1];
  const float* W_enc  = (const float*)d_in[2];
  const float* b_enc  = (const float*)d_in[3];
  const float* W_dec  = (const float*)d_in[4];
  const float* b_dec  = (const float*)d_in[5];
  const float* w_full = (const float*)d_in[6];
  // d_in[7] = b_full: softmax shift-invariant, unused.
  float* out = (float*)d_out;   // [awe 32*1024 | alpha 32*4096]

  char* ws = (char*)d_ws;
  float* att2  = (float*)ws;                                  // 64 KB
  short* Wfrag = (short*)(ws + 65536);                        // 1 MB
  float* e_buf = (float*)(ws + 65536 + 1048576);              // 1 MB (2 halves)
  float* part  = (float*)(ws + 65536 + 1048576 + 1048576);    // 2 MB

  hipLaunchKernelGGL(prep_kernel, dim3(B_ + 256), dim3(256), 0, stream,
                     dh, W_dec, b_dec, b_enc, W_enc, att2, Wfrag);
  hipLaunchKernelGGL(gemm_e_kernel, dim3(4096), dim3(256), 0, stream,
                     enc, Wfrag, att2, w_full, e_buf);
  hipLaunchKernelGGL(softmax_kernel, dim3(B_), dim3(256), 0, stream,
                     e_buf, out + B_ * ENC_);
  hipLaunchKernelGGL(awe_part_kernel, dim3(2048), dim3(256), 0, stream,
                     enc, out + B_ * ENC_, part);
  hipLaunchKernelGGL(awe_reduce_kernel, dim3(128), dim3(256), 0, stream,
                     part, out);
}

// Round 9
// 326.004 us; speedup vs baseline: 1.0925x; 1.0925x over previous
//
#include <hip/hip_runtime.h>

#define B_ 32
#define N_ 4096
#define ENC_ 1024
#define DEC_ 512
#define ATT_ 512

typedef __attribute__((ext_vector_type(8))) short short8;
typedef __attribute__((ext_vector_type(4))) float f32x4;
typedef __attribute__((ext_vector_type(4))) unsigned u32x4;

// fp32 -> bf16 bits, round-to-nearest-even (host-prep path)
__device__ __forceinline__ short f2bf(float f) {
  union { float f; unsigned u; } x; x.f = f;
  unsigned r = (x.u + 0x7FFFu + ((x.u >> 16) & 1u)) >> 16;
  return (short)r;
}

// HW packed convert: D[15:0]=bf16(a), D[31:16]=bf16(b). Non-volatile so the
// scheduler can hoist/interleave freely (m240: don't pin it).
__device__ __forceinline__ unsigned cvtpk(float a, float b) {
  unsigned r;
  asm("v_cvt_pk_bf16_f32 %0, %1, %2" : "=v"(r) : "v"(a), "v"(b));
  return r;
}

// async global->LDS DMA, 16B/lane; LDS dest = wave-uniform base + lane*16,
// global source is PER-LANE (pre-swizzled source implements the LDS swizzle).
__device__ __forceinline__ void gl_lds16(const float* g, void* l) {
  __builtin_amdgcn_global_load_lds(
      (const __attribute__((address_space(1))) unsigned int*)g,
      (__attribute__((address_space(3))) unsigned int*)l, 16, 0, 0);
}

// ---------------------------------------------------------------------------
// Kernel 1: (a) att2[b,a] = dh[b,:]@W_dec[:,a] + b_dec[a] + b_enc[a]
//           (b) W_enc fp32 -> bf16 in MFMA B-fragment order:
//               Wfrag[((c*32+g)*64+l)*8+j] = W_enc[g*32+(l>>4)*8+j][c*16+(l&15)]
// ---------------------------------------------------------------------------
extern "C" __global__ void __launch_bounds__(256) prep_kernel(
    const float* __restrict__ dh, const float* __restrict__ W_dec,
    const float* __restrict__ b_dec, const float* __restrict__ b_enc,
    const float* __restrict__ W_enc,
    float* __restrict__ att2, short* __restrict__ Wfrag)
{
  if (blockIdx.x < B_) {
    __shared__ float dhs[DEC_];
    int b = blockIdx.x;
    for (int i = threadIdx.x; i < DEC_; i += 256) dhs[i] = dh[b * DEC_ + i];
    __syncthreads();
    for (int a = threadIdx.x; a < ATT_; a += 256) {
      float s = b_dec[a] + b_enc[a];
      for (int k = 0; k < DEC_; ++k) s += dhs[k] * W_dec[k * ATT_ + a];
      att2[b * ATT_ + a] = s;
    }
  } else {
    int idx = (blockIdx.x - B_) * 256 + threadIdx.x;  // 0..65535 chunks of 8
    int l = idx & 63;          // lane
    int g = (idx >> 6) & 31;   // k-chunk (32 chunks of K=32)
    int c = idx >> 11;         // col-fragment (32 of 16 cols)
    int col = c * 16 + (l & 15);
    int kb = g * 32 + (l >> 4) * 8;
    short8 p;
#pragma unroll
    for (int j = 0; j < 8; ++j) p[j] = f2bf(W_enc[(kb + j) * ATT_ + col]);
    *(short8*)(Wfrag + ((long)idx << 3)) = p;
  }
}

// ---------------------------------------------------------------------------
// Kernel 2: fused  e_part[h,b,n] = sum_{a in half h} relu(att1+att2)*w
// R8 structure (proven: 2.7 blocks/CU, A read ~once) + two fixes:
//  - fragment build uses v_cvt_pk_bf16_f32 (4 inst/frag, was 32) -> VALU
//    content and ds_read->MFMA chain cut ~4x.
//  - B register double-buffer: load for sub-step ks+1 issued at top of ks
//    -> L2 latency off the critical path.
// A: fp32 via global_load_lds, XOR-swizzled via pre-swizzled per-lane SOURCE
//    (linear DMA dest), swizzled ds_read; convert at read via cvt_pk.
// ---------------------------------------------------------------------------
extern "C" __global__ void __launch_bounds__(256, 3) gemm_e_kernel(
    const float* __restrict__ enc, const short* __restrict__ Wfrag,
    const float* __restrict__ att2, const float* __restrict__ w_full,
    float* __restrict__ e_part)
{
  __shared__ __align__(16) float As[2][64 * 64];   // fp32, 16 KB each
  __shared__ float e_red[64][4];

  const int tid = threadIdx.x;
  const int lane = tid & 63;
  const int w = tid >> 6;          // wave 0..3 -> cols h*256 + w*64 ..
  const int blk = blockIdx.x;      // 4096 = 256 groups x {h=0:8, h=1:8}
  const int g16 = blk >> 4;
  const int h = (blk >> 3) & 1;    // column half
  const int p = g16 * 8 + (blk & 7);
  const int b = p >> 6;
  const int n0 = (p & 63) * 64;

  const int qv = lane >> 4;        // 0..3
  const int ch = lane & 15;        // 16B chunk within 64-float row slice

  // ---- A staging sources (inverse-swizzled). Wave w stages rows w*16..+15.
  const float* asrc[4];
#pragma unroll
  for (int j = 0; j < 4; ++j) {
    int rl = j * 4 + qv;
    asrc[j] = enc + (long)(b * N_ + n0 + w * 16 + rl) * ENC_ +
              ((ch ^ ((qv + (j & 1) * 4) & 7)) << 2);
  }

  // ---- A fragment read bases (swizzle mask m = lane&7 is r-independent):
  // addr(r,ks,half) = abase[half] + r*4096 + ks*128   (imm-foldable)
  const int abase0 = ch * 256 + (((qv * 2 + 0) ^ (ch & 7)) << 4);
  const int abase1 = ch * 256 + (((qv * 2 + 1) ^ (ch & 7)) << 4);

  // ---- B fragments: col-frag cf = h*16 + w*4 + cc, k-chunk g32 at
  // Wfrag[(cf*32+g32)*512 + lane*8]
  const short* bptr = Wfrag + (long)(h * 16 + w * 4) * 16384 + lane * 8;

  f32x4 acc[4][4] = {};
  short8 bfgA[4], bfgB[4];

  // ---- prologue: DMA-stage A(step 0) into As[0]; load B chunk 0
  {
    char* d = (char*)(&As[0][0]) + (w << 12);
#pragma unroll
    for (int j = 0; j < 4; ++j) gl_lds16(asrc[j], d + j * 1024);
  }
#pragma unroll
  for (int cc = 0; cc < 4; ++cc)
    bfgA[cc] = *(const short8*)(bptr + cc * 16384);
  __syncthreads();

  // ---- main K loop: 16 steps of BK=64 (2 sub-steps of K=32)
#pragma unroll
  for (int t = 0; t < 16; ++t) {
    const int cur = t & 1;
    // async prefetch A(t+1) into the other buffer (drained at end barrier)
    if (t + 1 < 16) {
      char* d = (char*)(&As[cur ^ 1][0]) + (w << 12);
#pragma unroll
      for (int j = 0; j < 4; ++j)
        gl_lds16(asrc[j] + (t + 1) * 64, d + j * 1024);
    }
    // ---- sub-step 0: compute with bfgA, prefetch chunk 2t+1 -> bfgB
    {
#pragma unroll
      for (int cc = 0; cc < 4; ++cc)
        bfgB[cc] = *(const short8*)(bptr + cc * 16384 + (2 * t + 1) * 512);
      short8 af[4];
#pragma unroll
      for (int r = 0; r < 4; ++r) {
        f32x4 lo = *(const f32x4*)((const char*)(&As[cur][0]) +
                                   (abase0 + r * 4096));
        f32x4 hi = *(const f32x4*)((const char*)(&As[cur][0]) +
                                   (abase1 + r * 4096));
        union { u32x4 u; short8 s; } cv;
        cv.u[0] = cvtpk(lo[0], lo[1]);
        cv.u[1] = cvtpk(lo[2], lo[3]);
        cv.u[2] = cvtpk(hi[0], hi[1]);
        cv.u[3] = cvtpk(hi[2], hi[3]);
        af[r] = cv.s;
      }
      __builtin_amdgcn_s_setprio(1);
#pragma unroll
      for (int cc = 0; cc < 4; ++cc)
#pragma unroll
        for (int r = 0; r < 4; ++r)
          acc[r][cc] = __builtin_amdgcn_mfma_f32_16x16x32_bf16(
              af[r], bfgA[cc], acc[r][cc], 0, 0, 0);
      __builtin_amdgcn_s_setprio(0);
    }
    // ---- sub-step 1: compute with bfgB, prefetch chunk 2t+2 -> bfgA
    {
      if (2 * t + 2 < 32) {
#pragma unroll
        for (int cc = 0; cc < 4; ++cc)
          bfgA[cc] = *(const short8*)(bptr + cc * 16384 + (2 * t + 2) * 512);
      }
      short8 af[4];
#pragma unroll
      for (int r = 0; r < 4; ++r) {
        f32x4 lo = *(const f32x4*)((const char*)(&As[cur][0]) +
                                   (abase0 + r * 4096 + 128));
        f32x4 hi = *(const f32x4*)((const char*)(&As[cur][0]) +
                                   (abase1 + r * 4096 + 128));
        union { u32x4 u; short8 s; } cv;
        cv.u[0] = cvtpk(lo[0], lo[1]);
        cv.u[1] = cvtpk(lo[2], lo[3]);
        cv.u[2] = cvtpk(hi[0], hi[1]);
        cv.u[3] = cvtpk(hi[2], hi[3]);
        af[r] = cv.s;
      }
      __builtin_amdgcn_s_setprio(1);
#pragma unroll
      for (int cc = 0; cc < 4; ++cc)
#pragma unroll
        for (int r = 0; r < 4; ++r)
          acc[r][cc] = __builtin_amdgcn_mfma_f32_16x16x32_bf16(
              af[r], bfgB[cc], acc[r][cc], 0, 0, 0);
      __builtin_amdgcn_s_setprio(0);
    }
    __syncthreads();   // drains A(t+1) DMA + all LDS reads of As[cur]
  }

  // ---- epilogue: partial e over this block's 256 cols
  const int lq = lane >> 4, lr = lane & 15;
  float at2v[4], wv[4];
#pragma unroll
  for (int c = 0; c < 4; ++c) {
    int col = h * 256 + w * 64 + c * 16 + lr;
    at2v[c] = att2[b * ATT_ + col];
    wv[c] = w_full[col];
  }
#pragma unroll
  for (int r = 0; r < 4; ++r) {
#pragma unroll
    for (int j = 0; j < 4; ++j) {
      float s = 0.f;
#pragma unroll
      for (int c = 0; c < 4; ++c)
        s += fmaxf(acc[r][c][j] + at2v[c], 0.f) * wv[c];
      s += __shfl_xor(s, 1); s += __shfl_xor(s, 2);
      s += __shfl_xor(s, 4); s += __shfl_xor(s, 8);
      if (lr == 0) e_red[r * 16 + lq * 4 + j][w] = s;
    }
  }
  __syncthreads();
  if (tid < 64) {
    float ev = e_red[tid][0] + e_red[tid][1] + e_red[tid][2] + e_red[tid][3];
    e_part[(long)h * (B_ * N_) + b * N_ + n0 + tid] = ev;
  }
}

// ---------------------------------------------------------------------------
// Kernel 3: softmax over N per batch, summing the two column-half partials.
// ---------------------------------------------------------------------------
extern "C" __global__ void __launch_bounds__(256) softmax_kernel(
    const float* __restrict__ e, float* __restrict__ alpha)
{
  int b = blockIdx.x, tid = threadIdx.x;
  float v[16];
  float m = -1e30f;
#pragma unroll
  for (int i = 0; i < 16; ++i) {
    int idx = b * N_ + i * 256 + tid;
    v[i] = e[idx] + e[B_ * N_ + idx];
    m = fmaxf(m, v[i]);
  }
  for (int off = 1; off < 64; off <<= 1) m = fmaxf(m, __shfl_xor(m, off));
  __shared__ float redm[4];
  if ((tid & 63) == 0) redm[tid >> 6] = m;
  __syncthreads();
  m = fmaxf(fmaxf(redm[0], redm[1]), fmaxf(redm[2], redm[3]));
  float s = 0.f;
#pragma unroll
  for (int i = 0; i < 16; ++i) { v[i] = expf(v[i] - m); s += v[i]; }
  for (int off = 1; off < 64; off <<= 1) s += __shfl_xor(s, off);
  __shared__ float reds[4];
  if ((tid & 63) == 0) reds[tid >> 6] = s;
  __syncthreads();
  s = reds[0] + reds[1] + reds[2] + reds[3];
  float inv = 1.0f / s;
#pragma unroll
  for (int i = 0; i < 16; ++i) alpha[b * N_ + i * 256 + tid] = v[i] * inv;
}

// ---------------------------------------------------------------------------
// Kernel 4: partial awe. grid = b(32) x cchunk(4, 256 cols) x nchunk(16, 256 n)
// ---------------------------------------------------------------------------
extern "C" __global__ void __launch_bounds__(256) awe_part_kernel(
    const float* __restrict__ enc, const float* __restrict__ alpha,
    float* __restrict__ part)
{
  __shared__ float als[256];
  __shared__ f32x4 red[256];
  int bi = blockIdx.x;
  int b = bi & 31, cchunk = (bi >> 5) & 3, nchunk = bi >> 7;
  int t = threadIdx.x;
  int n0 = nchunk * 256;
  als[t] = alpha[b * N_ + n0 + t];
  __syncthreads();
  int tcol = t & 63, tn = t >> 6;
  const float* base = enc + (long)b * N_ * ENC_ + (long)n0 * ENC_ +
                      cchunk * 256 + tcol * 4;
  f32x4 acc = {};
  for (int i = tn; i < 256; i += 4) {
    f32x4 vv = *(const f32x4*)(base + (long)i * ENC_);
    acc += als[i] * vv;
  }
  red[t] = acc;
  __syncthreads();
  if (t < 64) {
    f32x4 s = red[t] + red[t + 64] + red[t + 128] + red[t + 192];
    *(f32x4*)(&part[(long)nchunk * 32768 + b * 1024 + cchunk * 256 + t * 4]) = s;
  }
}

// Kernel 5: combine the 16 n-partials
extern "C" __global__ void __launch_bounds__(256) awe_reduce_kernel(
    const float* __restrict__ part, float* __restrict__ awe)
{
  int i = blockIdx.x * 256 + threadIdx.x;   // 32768 = 32*1024
  float s = 0.f;
#pragma unroll
  for (int p = 0; p < 16; ++p) s += part[(long)p * 32768 + i];
  awe[i] = s;
}

// ---------------------------------------------------------------------------
extern "C" void kernel_launch(void* const* d_in, const int* in_sizes, int n_in,
                              void* d_out, int out_size, void* d_ws, size_t ws_size,
                              hipStream_t stream) {
  const float* enc    = (const float*)d_in[0];
  const float* dh     = (const float*)d_in[1];
  const float* W_enc  = (const float*)d_in[2];
  const float* b_enc  = (const float*)d_in[3];
  const float* W_dec  = (const float*)d_in[4];
  const float* b_dec  = (const float*)d_in[5];
  const float* w_full = (const float*)d_in[6];
  // d_in[7] = b_full: softmax shift-invariant, unused.
  float* out = (float*)d_out;   // [awe 32*1024 | alpha 32*4096]

  char* ws = (char*)d_ws;
  float* att2  = (float*)ws;                                  // 64 KB
  short* Wfrag = (short*)(ws + 65536);                        // 1 MB
  float* e_buf = (float*)(ws + 65536 + 1048576);              // 1 MB (2 halves)
  float* part  = (float*)(ws + 65536 + 1048576 + 1048576);    // 2 MB

  hipLaunchKernelGGL(prep_kernel, dim3(B_ + 256), dim3(256), 0, stream,
                     dh, W_dec, b_dec, b_enc, W_enc, att2, Wfrag);
  hipLaunchKernelGGL(gemm_e_kernel, dim3(4096), dim3(256), 0, stream,
                     enc, Wfrag, att2, w_full, e_buf);
  hipLaunchKernelGGL(softmax_kernel, dim3(B_), dim3(256), 0, stream,
                     e_buf, out + B_ * ENC_);
  hipLaunchKernelGGL(awe_part_kernel, dim3(2048), dim3(256), 0, stream,
                     enc, out + B_ * ENC_, part);
  hipLaunchKernelGGL(awe_reduce_kernel, dim3(128), dim3(256), 0, stream,
                     part, out);
}

// Round 10
// 324.100 us; speedup vs baseline: 1.0989x; 1.0059x over previous
//
#include <hip/hip_runtime.h>

#define B_ 32
#define N_ 4096
#define ENC_ 1024
#define DEC_ 512
#define ATT_ 512

typedef __attribute__((ext_vector_type(8))) short short8;
typedef __attribute__((ext_vector_type(4))) float f32x4;
typedef __attribute__((ext_vector_type(4))) unsigned u32x4;

// fp32 -> bf16 bits, round-to-nearest-even (host-prep path)
__device__ __forceinline__ short f2bf(float f) {
  union { float f; unsigned u; } x; x.f = f;
  unsigned r = (x.u + 0x7FFFu + ((x.u >> 16) & 1u)) >> 16;
  return (short)r;
}

// HW packed convert: D[15:0]=bf16(a), D[31:16]=bf16(b). Non-volatile so the
// scheduler can interleave freely.
__device__ __forceinline__ unsigned cvtpk(float a, float b) {
  unsigned r;
  asm("v_cvt_pk_bf16_f32 %0, %1, %2" : "=v"(r) : "v"(a), "v"(b));
  return r;
}

// async global->LDS DMA, 16B/lane; LDS dest = wave-uniform base + lane*16,
// global source is PER-LANE (pre-swizzled source implements the LDS swizzle).
__device__ __forceinline__ void gl_lds16(const float* g, void* l) {
  __builtin_amdgcn_global_load_lds(
      (const __attribute__((address_space(1))) unsigned int*)g,
      (__attribute__((address_space(3))) unsigned int*)l, 16, 0, 0);
}

// ---------------------------------------------------------------------------
// Kernel 1: (a) att2[b,a] = dh[b,:]@W_dec[:,a] + b_dec[a] + b_enc[a]
//           (b) W_enc fp32 -> bf16 in MFMA B-fragment order:
//               Wfrag[((c*32+g)*64+l)*8+j] = W_enc[g*32+(l>>4)*8+j][c*16+(l&15)]
// ---------------------------------------------------------------------------
extern "C" __global__ void __launch_bounds__(256) prep_kernel(
    const float* __restrict__ dh, const float* __restrict__ W_dec,
    const float* __restrict__ b_dec, const float* __restrict__ b_enc,
    const float* __restrict__ W_enc,
    float* __restrict__ att2, short* __restrict__ Wfrag)
{
  if (blockIdx.x < B_) {
    __shared__ float dhs[DEC_];
    int b = blockIdx.x;
    for (int i = threadIdx.x; i < DEC_; i += 256) dhs[i] = dh[b * DEC_ + i];
    __syncthreads();
    for (int a = threadIdx.x; a < ATT_; a += 256) {
      float s = b_dec[a] + b_enc[a];
      for (int k = 0; k < DEC_; ++k) s += dhs[k] * W_dec[k * ATT_ + a];
      att2[b * ATT_ + a] = s;
    }
  } else {
    int idx = (blockIdx.x - B_) * 256 + threadIdx.x;  // 0..65535 chunks of 8
    int l = idx & 63;          // lane
    int g = (idx >> 6) & 31;   // k-chunk (32 chunks of K=32)
    int c = idx >> 11;         // col-fragment (32 of 16 cols)
    int col = c * 16 + (l & 15);
    int kb = g * 32 + (l >> 4) * 8;
    short8 p;
#pragma unroll
    for (int j = 0; j < 8; ++j) p[j] = f2bf(W_enc[(kb + j) * ATT_ + col]);
    *(short8*)(Wfrag + ((long)idx << 3)) = p;
  }
}

// ---------------------------------------------------------------------------
// Kernel 2: fused  e_part[h,b,n] = sum_{a in half h} relu(att1+att2)*w
// R9 structure + THE vmcnt de-entanglement fix:
//   vmcnt retires IN ISSUE ORDER, so any wait on a load issued AFTER the
//   A(t+1) HBM DMA forces the DMA to drain mid-step (the 18%-MfmaUtil
//   serializer of R2-R9). Fix: per step, issue ALL 8 B(t) loads FIRST,
//   then the 4 DMAs, fenced by sched_barrier(0). B-waits now drain only B;
//   the DMA drains exactly once per step at the end barrier, after a full
//   step (~2x HBM latency) in flight.
// ---------------------------------------------------------------------------
extern "C" __global__ void __launch_bounds__(256, 3) gemm_e_kernel(
    const float* __restrict__ enc, const short* __restrict__ Wfrag,
    const float* __restrict__ att2, const float* __restrict__ w_full,
    float* __restrict__ e_part)
{
  __shared__ __align__(16) float As[2][64 * 64];   // fp32, 16 KB each
  __shared__ float e_red[64][4];

  const int tid = threadIdx.x;
  const int lane = tid & 63;
  const int w = tid >> 6;          // wave 0..3 -> cols h*256 + w*64 ..
  const int blk = blockIdx.x;      // 4096 = 256 groups x {h=0:8, h=1:8}
  const int g16 = blk >> 4;
  const int h = (blk >> 3) & 1;    // column half
  const int p = g16 * 8 + (blk & 7);
  const int b = p >> 6;
  const int n0 = (p & 63) * 64;

  const int qv = lane >> 4;        // 0..3
  const int ch = lane & 15;        // 16B chunk within 64-float row slice

  // ---- A staging sources (inverse-swizzled). Wave w stages rows w*16..+15.
  const float* asrc[4];
#pragma unroll
  for (int j = 0; j < 4; ++j) {
    int rl = j * 4 + qv;
    asrc[j] = enc + (long)(b * N_ + n0 + w * 16 + rl) * ENC_ +
              ((ch ^ ((qv + (j & 1) * 4) & 7)) << 2);
  }

  // ---- A fragment read bases (swizzle mask m = lane&7 is r-independent):
  // addr(r,ks,half) = abase[half] + r*4096 + ks*128   (imm-foldable)
  const int abase0 = ch * 256 + (((qv * 2 + 0) ^ (ch & 7)) << 4);
  const int abase1 = ch * 256 + (((qv * 2 + 1) ^ (ch & 7)) << 4);

  // ---- B fragments: col-frag cf = h*16 + w*4 + cc, k-chunk g32 at
  // Wfrag[(cf*32+g32)*512 + lane*8]
  const short* bptr = Wfrag + (long)(h * 16 + w * 4) * 16384 + lane * 8;

  f32x4 acc[4][4] = {};

  // ---- prologue: DMA-stage A(step 0) into As[0]
  {
    char* d = (char*)(&As[0][0]) + (w << 12);
#pragma unroll
    for (int j = 0; j < 4; ++j) gl_lds16(asrc[j], d + j * 1024);
  }
  __syncthreads();

  // ---- main K loop: 16 steps of BK=64 (2 sub-steps of K=32)
#pragma unroll
  for (int t = 0; t < 16; ++t) {
    const int cur = t & 1;

    // ===== VMEM issue phase. ORDER IS THE WHOLE POINT: B first... =====
    short8 bfg[8];
#pragma unroll
    for (int cc = 0; cc < 4; ++cc)
      bfg[cc] = *(const short8*)(bptr + cc * 16384 + (2 * t) * 512);
#pragma unroll
    for (int cc = 0; cc < 4; ++cc)
      bfg[4 + cc] = *(const short8*)(bptr + cc * 16384 + (2 * t + 1) * 512);
    __builtin_amdgcn_sched_barrier(0);
    // ===== ...then the A(t+1) DMA (drained only at the step-end barrier).
    if (t + 1 < 16) {
      char* d = (char*)(&As[cur ^ 1][0]) + (w << 12);
#pragma unroll
      for (int j = 0; j < 4; ++j)
        gl_lds16(asrc[j] + (t + 1) * 64, d + j * 1024);
    }
    __builtin_amdgcn_sched_barrier(0);

    // ===== compute: sub-step 0 (bfg[0..3]) =====
    {
      short8 af[4];
#pragma unroll
      for (int r = 0; r < 4; ++r) {
        f32x4 lo = *(const f32x4*)((const char*)(&As[cur][0]) +
                                   (abase0 + r * 4096));
        f32x4 hi = *(const f32x4*)((const char*)(&As[cur][0]) +
                                   (abase1 + r * 4096));
        union { u32x4 u; short8 s; } cv;
        cv.u[0] = cvtpk(lo[0], lo[1]);
        cv.u[1] = cvtpk(lo[2], lo[3]);
        cv.u[2] = cvtpk(hi[0], hi[1]);
        cv.u[3] = cvtpk(hi[2], hi[3]);
        af[r] = cv.s;
      }
      __builtin_amdgcn_s_setprio(1);
#pragma unroll
      for (int cc = 0; cc < 4; ++cc)
#pragma unroll
        for (int r = 0; r < 4; ++r)
          acc[r][cc] = __builtin_amdgcn_mfma_f32_16x16x32_bf16(
              af[r], bfg[cc], acc[r][cc], 0, 0, 0);
      __builtin_amdgcn_s_setprio(0);
    }
    // ===== compute: sub-step 1 (bfg[4..7]) =====
    {
      short8 af[4];
#pragma unroll
      for (int r = 0; r < 4; ++r) {
        f32x4 lo = *(const f32x4*)((const char*)(&As[cur][0]) +
                                   (abase0 + r * 4096 + 128));
        f32x4 hi = *(const f32x4*)((const char*)(&As[cur][0]) +
                                   (abase1 + r * 4096 + 128));
        union { u32x4 u; short8 s; } cv;
        cv.u[0] = cvtpk(lo[0], lo[1]);
        cv.u[1] = cvtpk(lo[2], lo[3]);
        cv.u[2] = cvtpk(hi[0], hi[1]);
        cv.u[3] = cvtpk(hi[2], hi[3]);
        af[r] = cv.s;
      }
      __builtin_amdgcn_s_setprio(1);
#pragma unroll
      for (int cc = 0; cc < 4; ++cc)
#pragma unroll
        for (int r = 0; r < 4; ++r)
          acc[r][cc] = __builtin_amdgcn_mfma_f32_16x16x32_bf16(
              af[r], bfg[4 + cc], acc[r][cc], 0, 0, 0);
      __builtin_amdgcn_s_setprio(0);
    }
    __syncthreads();   // single full drain per step: DMA had a whole step
  }

  // ---- epilogue: partial e over this block's 256 cols
  const int lq = lane >> 4, lr = lane & 15;
  float at2v[4], wv[4];
#pragma unroll
  for (int c = 0; c < 4; ++c) {
    int col = h * 256 + w * 64 + c * 16 + lr;
    at2v[c] = att2[b * ATT_ + col];
    wv[c] = w_full[col];
  }
#pragma unroll
  for (int r = 0; r < 4; ++r) {
#pragma unroll
    for (int j = 0; j < 4; ++j) {
      float s = 0.f;
#pragma unroll
      for (int c = 0; c < 4; ++c)
        s += fmaxf(acc[r][c][j] + at2v[c], 0.f) * wv[c];
      s += __shfl_xor(s, 1); s += __shfl_xor(s, 2);
      s += __shfl_xor(s, 4); s += __shfl_xor(s, 8);
      if (lr == 0) e_red[r * 16 + lq * 4 + j][w] = s;
    }
  }
  __syncthreads();
  if (tid < 64) {
    float ev = e_red[tid][0] + e_red[tid][1] + e_red[tid][2] + e_red[tid][3];
    e_part[(long)h * (B_ * N_) + b * N_ + n0 + tid] = ev;
  }
}

// ---------------------------------------------------------------------------
// Kernel 3: softmax over N per batch, summing the two column-half partials.
// ---------------------------------------------------------------------------
extern "C" __global__ void __launch_bounds__(256) softmax_kernel(
    const float* __restrict__ e, float* __restrict__ alpha)
{
  int b = blockIdx.x, tid = threadIdx.x;
  float v[16];
  float m = -1e30f;
#pragma unroll
  for (int i = 0; i < 16; ++i) {
    int idx = b * N_ + i * 256 + tid;
    v[i] = e[idx] + e[B_ * N_ + idx];
    m = fmaxf(m, v[i]);
  }
  for (int off = 1; off < 64; off <<= 1) m = fmaxf(m, __shfl_xor(m, off));
  __shared__ float redm[4];
  if ((tid & 63) == 0) redm[tid >> 6] = m;
  __syncthreads();
  m = fmaxf(fmaxf(redm[0], redm[1]), fmaxf(redm[2], redm[3]));
  float s = 0.f;
#pragma unroll
  for (int i = 0; i < 16; ++i) { v[i] = expf(v[i] - m); s += v[i]; }
  for (int off = 1; off < 64; off <<= 1) s += __shfl_xor(s, off);
  __shared__ float reds[4];
  if ((tid & 63) == 0) reds[tid >> 6] = s;
  __syncthreads();
  s = reds[0] + reds[1] + reds[2] + reds[3];
  float inv = 1.0f / s;
#pragma unroll
  for (int i = 0; i < 16; ++i) alpha[b * N_ + i * 256 + tid] = v[i] * inv;
}

// ---------------------------------------------------------------------------
// Kernel 4: partial awe. grid = b(32) x cchunk(4, 256 cols) x nchunk(16, 256 n)
// ---------------------------------------------------------------------------
extern "C" __global__ void __launch_bounds__(256) awe_part_kernel(
    const float* __restrict__ enc, const float* __restrict__ alpha,
    float* __restrict__ part)
{
  __shared__ float als[256];
  __shared__ f32x4 red[256];
  int bi = blockIdx.x;
  int b = bi & 31, cchunk = (bi >> 5) & 3, nchunk = bi >> 7;
  int t = threadIdx.x;
  int n0 = nchunk * 256;
  als[t] = alpha[b * N_ + n0 + t];
  __syncthreads();
  int tcol = t & 63, tn = t >> 6;
  const float* base = enc + (long)b * N_ * ENC_ + (long)n0 * ENC_ +
                      cchunk * 256 + tcol * 4;
  f32x4 acc = {};
  for (int i = tn; i < 256; i += 4) {
    f32x4 vv = *(const f32x4*)(base + (long)i * ENC_);
    acc += als[i] * vv;
  }
  red[t] = acc;
  __syncthreads();
  if (t < 64) {
    f32x4 s = red[t] + red[t + 64] + red[t + 128] + red[t + 192];
    *(f32x4*)(&part[(long)nchunk * 32768 + b * 1024 + cchunk * 256 + t * 4]) = s;
  }
}

// Kernel 5: combine the 16 n-partials
extern "C" __global__ void __launch_bounds__(256) awe_reduce_kernel(
    const float* __restrict__ part, float* __restrict__ awe)
{
  int i = blockIdx.x * 256 + threadIdx.x;   // 32768 = 32*1024
  float s = 0.f;
#pragma unroll
  for (int p = 0; p < 16; ++p) s += part[(long)p * 32768 + i];
  awe[i] = s;
}

// ---------------------------------------------------------------------------
extern "C" void kernel_launch(void* const* d_in, const int* in_sizes, int n_in,
                              void* d_out, int out_size, void* d_ws, size_t ws_size,
                              hipStream_t stream) {
  const float* enc    = (const float*)d_in[0];
  const float* dh     = (const float*)d_in[1];
  const float* W_enc  = (const float*)d_in[2];
  const float* b_enc  = (const float*)d_in[3];
  const float* W_dec  = (const float*)d_in[4];
  const float* b_dec  = (const float*)d_in[5];
  const float* w_full = (const float*)d_in[6];
  // d_in[7] = b_full: softmax shift-invariant, unused.
  float* out = (float*)d_out;   // [awe 32*1024 | alpha 32*4096]

  char* ws = (char*)d_ws;
  float* att2  = (float*)ws;                                  // 64 KB
  short* Wfrag = (short*)(ws + 65536);                        // 1 MB
  float* e_buf = (float*)(ws + 65536 + 1048576);              // 1 MB (2 halves)
  float* part  = (float*)(ws + 65536 + 1048576 + 1048576);    // 2 MB

  hipLaunchKernelGGL(prep_kernel, dim3(B_ + 256), dim3(256), 0, stream,
                     dh, W_dec, b_dec, b_enc, W_enc, att2, Wfrag);
  hipLaunchKernelGGL(gemm_e_kernel, dim3(4096), dim3(256), 0, stream,
                     enc, Wfrag, att2, w_full, e_buf);
  hipLaunchKernelGGL(softmax_kernel, dim3(B_), dim3(256), 0, stream,
                     e_buf, out + B_ * ENC_);
  hipLaunchKernelGGL(awe_part_kernel, dim3(2048), dim3(256), 0, stream,
                     enc, out + B_ * ENC_, part);
  hipLaunchKernelGGL(awe_reduce_kernel, dim3(128), dim3(256), 0, stream,
                     part, out);
}